// Round 3
// baseline (500.310 us; speedup 1.0000x reference)
//
#include <hip/hip_runtime.h>
#include <math.h>

#define N_TOKENS 16384
#define D_MODEL  4096
#define N_EXP    64

#define BK   16                 // k-depth per LDS x-tile
#define LD   68                 // LDS leading dim: 64 + 4 pad (16B align, 2-way banks)
#define NW   8                  // waves per block
#define KW   (D_MODEL / NW)     // 512 k per wave (wave-level k-split)
#define NT   (KW / BK)          // 32 tiles per wave
#define NBLK (N_TOKENS / 64)    // 256 blocks

// ---------------------------------------------------------------------------
// Pre-pass: w[64][4096] -> wT[4096][64] so per-k expert fragments are
// contiguous in global memory (2x global_load_dwordx4 per k-step, L1/L2-hot).
// 64 blocks x 64-k tiles, LDS transpose, fully coalesced both sides. ~5 us.
// ---------------------------------------------------------------------------
__global__ void __launch_bounds__(256)
transpose_w(const float* __restrict__ w, float* __restrict__ wt) {
    __shared__ float t[64][LD];
    const int k0 = blockIdx.x * 64;
    const int kc = (threadIdx.x & 15) * 4;   // k offset within tile
    const int e0 = threadIdx.x >> 4;         // 0..15
#pragma unroll
    for (int p = 0; p < 4; ++p) {
        int e = p * 16 + e0;
        float4 v = *(const float4*)(w + (size_t)e * D_MODEL + k0 + kc);
        t[kc + 0][e] = v.x; t[kc + 1][e] = v.y;
        t[kc + 2][e] = v.z; t[kc + 3][e] = v.w;
    }
    __syncthreads();
    const int kr = threadIdx.x >> 2;         // 0..63
    const int ec = (threadIdx.x & 3) * 16;
#pragma unroll
    for (int j = 0; j < 4; ++j) {
        float4 v = make_float4(t[kr][ec + j * 4 + 0], t[kr][ec + j * 4 + 1],
                               t[kr][ec + j * 4 + 2], t[kr][ec + j * 4 + 3]);
        *(float4*)(wt + (size_t)(k0 + kr) * N_EXP + ec + j * 4) = v;
    }
}

// ---------------------------------------------------------------------------
// Fused router. Block = 64 tokens, 512 threads = 8 waves; wave wv owns the
// full 64x64 logit tile for k in [wv*512, wv*512+512).
//   - x staged in per-wave double-buffered LDS ([k][token], transposed on
//     store); 2 ds_read_b128 per k-step -> LDS pipe demand 4x24 = 96 cyc per
//     128 wall cyc: VALU-bound (round-2's w-in-LDS was 192/128, LDS-bound)
//   - w read straight from wT (global, L1/L2-resident): 2 dwordx4 per k-step
//   - NO barriers in main loop; no spills (VGPR <= 128 fits with w out of LDS)
//   - LDS 69.6 KB/block -> 2 blocks/CU; launch_bounds(512,4) -> 4 waves/SIMD
// Epilogue: 2-stage tile reduce (waves 0-3 write 4 tiles, waves 4-7 RMW-add),
// softmax/top2 with ballot-argmax (ties -> lowest index), block p/f sums.
// ---------------------------------------------------------------------------
__global__ void __launch_bounds__(512, 4)
router_fused(const float* __restrict__ x, const float* __restrict__ wt,
             float* __restrict__ out, float* __restrict__ block_sums) {
    // staging: per wave 2 x [BK][LD] = 2176 floats; 8 waves = 17408 floats.
    // epilogue reuse: 4 x [64][64] tiles at [0,16384), p/f sums at [16384,17408).
    __shared__ float smem[NW * 2 * BK * LD];   // 69632 B -> 2 blocks/CU

    const int tid  = threadIdx.x;
    const int wv   = tid >> 6;
    const int lane = tid & 63;
    const int tok0 = blockIdx.x * 64;

    float* xs = smem + wv * (2 * BK * LD);   // this wave's x double-buffer

    // staging: lane covers token rows {srow,+16,+32,+48}, k-chunk skc..skc+3
    const int srow = lane >> 2;          // 0..15
    const int skc  = (lane & 3) * 4;     // 0,4,8,12

    // compute: 8x8 micro-tile
    const int trow = (lane & 7) * 8;     // first of 8 tokens
    const int ecol = (lane >> 3) * 8;    // first of 8 experts

    const float* xp = x + (size_t)(tok0 + srow) * D_MODEL + (size_t)wv * KW + skc;
    const float* wp = wt + (size_t)wv * KW * N_EXP + ecol;   // row k: wp + k*64

    float acc[8][8] = {};

#define LOADR(q, roff) (*(const float4*)((q) + (size_t)(roff) * D_MODEL))
#define STORE_TILE(buf, v, roff) do {                      \
        (buf)[(skc + 0) * LD + srow + (roff)] = (v).x;     \
        (buf)[(skc + 1) * LD + srow + (roff)] = (v).y;     \
        (buf)[(skc + 2) * LD + srow + (roff)] = (v).z;     \
        (buf)[(skc + 3) * LD + srow + (roff)] = (v).w;     \
    } while (0)

    // prologue: x tile 0 -> buffer 0
    {
        float4 a0 = LOADR(xp, 0),  a1 = LOADR(xp, 16);
        float4 a2 = LOADR(xp, 32), a3 = LOADR(xp, 48);
        STORE_TILE(xs, a0, 0);  STORE_TILE(xs, a1, 16);
        STORE_TILE(xs, a2, 32); STORE_TILE(xs, a3, 48);
    }

    auto compute_tile = [&](const float* xb, int kbase) {
#pragma unroll 4
        for (int k = 0; k < BK; ++k) {
            const float* xr = xb + k * LD + trow;
            float4 xa = *(const float4*)xr;
            float4 xc = *(const float4*)(xr + 4);
            const float* wr = wp + (size_t)(kbase + k) * N_EXP;
            float4 wa = *(const float4*)wr;
            float4 wc = *(const float4*)(wr + 4);
            float xf[8] = {xa.x, xa.y, xa.z, xa.w, xc.x, xc.y, xc.z, xc.w};
            float wf[8] = {wa.x, wa.y, wa.z, wa.w, wc.x, wc.y, wc.z, wc.w};
#pragma unroll
            for (int i = 0; i < 8; ++i)
#pragma unroll
                for (int j = 0; j < 8; ++j)
                    acc[i][j] = fmaf(xf[i], wf[j], acc[i][j]);
        }
    };

    for (int t = 0; t < NT - 1; ++t) {
        float* xb = xs + (t & 1) * (BK * LD);
        float* xn = xs + ((t + 1) & 1) * (BK * LD);

        // issue next x tile's global loads; latency hides under 2048cyc of FMA
        const float* xq = xp + (t + 1) * BK;
        float4 a0 = LOADR(xq, 0),  a1 = LOADR(xq, 16);
        float4 a2 = LOADR(xq, 32), a3 = LOADR(xq, 48);

        compute_tile(xb, t * BK);

        STORE_TILE(xn, a0, 0);  STORE_TILE(xn, a1, 16);
        STORE_TILE(xn, a2, 32); STORE_TILE(xn, a3, 48);
    }
    compute_tile(xs + ((NT - 1) & 1) * (BK * LD), (NT - 1) * BK);

    // ---- epilogue: 2-stage cross-wave k-reduce + softmax/top2 ----
    __syncthreads();                       // all waves done with staging reads

    float* tile = smem + (wv & 3) * 4096;  // 4 shared 64x64 tiles
    if (wv < 4) {
#pragma unroll
        for (int i = 0; i < 8; ++i) {
            *(float4*)&tile[(trow + i) * 64 + ecol] =
                make_float4(acc[i][0], acc[i][1], acc[i][2], acc[i][3]);
            *(float4*)&tile[(trow + i) * 64 + ecol + 4] =
                make_float4(acc[i][4], acc[i][5], acc[i][6], acc[i][7]);
        }
    }
    __syncthreads();
    if (wv >= 4) {                         // RMW-add (disjoint elements/thread)
#pragma unroll
        for (int i = 0; i < 8; ++i) {
            float4* tp = (float4*)&tile[(trow + i) * 64 + ecol];
            float4 v0 = tp[0], v1 = tp[1];
            v0.x += acc[i][0]; v0.y += acc[i][1];
            v0.z += acc[i][2]; v0.w += acc[i][3];
            v1.x += acc[i][4]; v1.y += acc[i][5];
            v1.z += acc[i][6]; v1.w += acc[i][7];
            tp[0] = v0; tp[1] = v1;
        }
    }
    __syncthreads();

    float p_acc = 0.f, f_acc = 0.f;        // lane = expert
#pragma unroll 1
    for (int it = 0; it < 8; ++it) {
        const int tl = wv * 8 + it;        // local token
        const int o  = tl * 64 + lane;
        float logit = smem[o] + smem[4096 + o] + smem[8192 + o] + smem[12288 + o];

        // top-1: value max-reduce, then ballot -> lowest tied index
        float m = logit;
#pragma unroll
        for (int off = 32; off; off >>= 1)
            m = fmaxf(m, __shfl_xor(m, off, 64));
        unsigned long long b1 = __ballot(logit == m);
        int i1 = __ffsll(b1) - 1;

        float p = expf(logit - m);
        float denom = p;
#pragma unroll
        for (int off = 32; off; off >>= 1)
            denom += __shfl_xor(denom, off, 64);

        p_acc += p / denom;                // router_probs[token][lane]
        if (lane == i1) f_acc += 1.f;

        // top-2: mask i1, repeat
        float lx = (lane == i1) ? -__builtin_inff() : logit;
        float m2 = lx;
#pragma unroll
        for (int off = 32; off; off >>= 1)
            m2 = fmaxf(m2, __shfl_xor(m2, off, 64));
        unsigned long long b2 = __ballot(lx == m2);
        int i2 = __ffsll(b2) - 1;

        if (lane == 0) {
            float p1 = 1.0f / denom;               // exp(m-m)/denom
            float p2 = expf(m2 - m) / denom;
            float s12 = p1 + p2;
            int token = tok0 + tl;
            ((float2*)out)[token] = make_float2(p1 / s12, p2 / s12);
            ((float2*)(out + 2 * N_TOKENS))[token] =
                make_float2((float)i1, (float)i2);
        }
    }

    // block-level p/f sums -> block_sums (no atomics)
    float* pf = smem + 4 * 4096;           // [0,512): p, [512,1024): f
    pf[wv * 64 + lane]       = p_acc;
    pf[512 + wv * 64 + lane] = f_acc;
    __syncthreads();
    if (tid < N_EXP) {
        float ps = 0.f, fs = 0.f;
#pragma unroll
        for (int h = 0; h < NW; ++h) {
            ps += pf[h * 64 + tid];
            fs += pf[512 + h * 64 + tid];
        }
        block_sums[(size_t)blockIdx.x * 128 + tid]      = ps;
        block_sums[(size_t)blockIdx.x * 128 + 64 + tid] = fs;
    }
}

// ---------------------------------------------------------------------------
// Final: reduce 256 blocks' p/f sums, loss = 0.01 * sum_e (f_e/N)*(p_e/N).
// ---------------------------------------------------------------------------
__global__ void __launch_bounds__(256)
router_final(const float* __restrict__ block_sums, float* __restrict__ out) {
    __shared__ float sp[4][N_EXP];
    __shared__ float sf[4][N_EXP];

    int tid  = threadIdx.x;
    int wv   = tid >> 6;
    int lane = tid & 63;

    float ps = 0.f, fs = 0.f;
#pragma unroll 8
    for (int b = wv * (NBLK / 4); b < (wv + 1) * (NBLK / 4); ++b) {
        ps += block_sums[(size_t)b * 128 + lane];
        fs += block_sums[(size_t)b * 128 + 64 + lane];
    }
    sp[wv][lane] = ps;
    sf[wv][lane] = fs;
    __syncthreads();

    if (tid < N_EXP) {
        float pt = sp[0][tid] + sp[1][tid] + sp[2][tid] + sp[3][tid];
        float ft = sf[0][tid] + sf[1][tid] + sf[2][tid] + sf[3][tid];
        float v = pt * ft;
#pragma unroll
        for (int off = 1; off < 64; off <<= 1)
            v += __shfl_xor(v, off, 64);
        if (tid == 0)
            out[4 * N_TOKENS] = 0.01f * v / ((float)N_TOKENS * (float)N_TOKENS);
    }
}

// ---------------------------------------------------------------------------
extern "C" void kernel_launch(void* const* d_in, const int* in_sizes, int n_in,
                              void* d_out, int out_size, void* d_ws, size_t ws_size,
                              hipStream_t stream) {
    (void)in_sizes; (void)n_in; (void)out_size; (void)ws_size;
    const float* x = (const float*)d_in[0];
    const float* w = (const float*)d_in[1];
    float* out = (float*)d_out;

    float* wT = (float*)d_ws;                            // 4096*64*4 = 1 MB
    float* block_sums = wT + (size_t)D_MODEL * N_EXP;    // 128 KB

    transpose_w<<<D_MODEL / 64, 256, 0, stream>>>(w, wT);
    router_fused<<<NBLK, 512, 0, stream>>>(x, wT, out, block_sums);
    router_final<<<1, 256, 0, stream>>>(block_sums, out);
}

// Round 4
// 499.694 us; speedup vs baseline: 1.0012x; 1.0012x over previous
//
#include <hip/hip_runtime.h>
#include <math.h>

#define N_TOKENS 16384
#define D_MODEL  4096
#define N_EXP    64

#define BK   16                 // k-depth per LDS x-tile
#define LD   68                 // LDS leading dim: 64 + 4 pad (16B align, 2-way banks)
#define NW   8                  // waves per block
#define KW   (D_MODEL / NW)     // 512 k per wave (wave-level k-split)
#define NT   (KW / BK)          // 32 tiles per wave
#define NBLK (N_TOKENS / 64)    // 256 blocks

// ---------------------------------------------------------------------------
// Pre-pass: w[64][4096] -> wT[4096][64] so per-k expert fragments are
// contiguous in global memory (2x global_load_dwordx4 per k-step, L2-hot).
// ---------------------------------------------------------------------------
__global__ void __launch_bounds__(256)
transpose_w(const float* __restrict__ w, float* __restrict__ wt) {
    __shared__ float t[64][LD];
    const int k0 = blockIdx.x * 64;
    const int kc = (threadIdx.x & 15) * 4;   // k offset within tile
    const int e0 = threadIdx.x >> 4;         // 0..15
#pragma unroll
    for (int p = 0; p < 4; ++p) {
        int e = p * 16 + e0;
        float4 v = *(const float4*)(w + (size_t)e * D_MODEL + k0 + kc);
        t[kc + 0][e] = v.x; t[kc + 1][e] = v.y;
        t[kc + 2][e] = v.z; t[kc + 3][e] = v.w;
    }
    __syncthreads();
    const int kr = threadIdx.x >> 2;         // 0..63
    const int ec = (threadIdx.x & 3) * 16;
#pragma unroll
    for (int j = 0; j < 4; ++j) {
        float4 v = make_float4(t[kr][ec + j * 4 + 0], t[kr][ec + j * 4 + 1],
                               t[kr][ec + j * 4 + 2], t[kr][ec + j * 4 + 3]);
        *(float4*)(wt + (size_t)(k0 + kr) * N_EXP + ec + j * 4) = v;
    }
}

// ---------------------------------------------------------------------------
// Fused router. Block = 64 tokens, 512 threads = 8 waves; wave wv owns the
// full 64x64 logit tile for k in [wv*512, wv*512+512).
//   - x staged in per-wave double-buffered LDS; 2 ds_read_b128 per k-step
//     -> CU LDS-pipe demand 4x24 = 96 cyc per 128 FMA cyc: VALU-bound
//   - w read straight from wT (global, L2-resident): 2 dwordx4 per k-step
//   - NO barriers in main loop
//   - launch_bounds(512,2) -> VGPR cap 128 (round 3's (512,4) clamped to 64
//     VGPRs and serialized; round 2's 128-cap structure spilled because w's
//     LDS prefetch held 20 extra live regs — this structure needs ~106)
//   - LDS 69.6 KB -> 2 blocks/CU; VGPR<=128 -> 4 waves/SIMD realized
// Epilogue: 2-stage tile reduce (waves 0-3 write 4 tiles, waves 4-7 RMW-add),
// softmax/top2 with ballot-argmax (ties -> lowest index), block p/f sums.
// ---------------------------------------------------------------------------
__global__ void __launch_bounds__(512, 2)
router_fused(const float* __restrict__ x, const float* __restrict__ wt,
             float* __restrict__ out, float* __restrict__ block_sums) {
    // staging: per wave 2 x [BK][LD] = 2176 floats; 8 waves = 17408 floats.
    // epilogue reuse: 4 x [64][64] tiles at [0,16384), p/f sums at [16384,17408).
    __shared__ float smem[NW * 2 * BK * LD];   // 69632 B -> 2 blocks/CU

    const int tid  = threadIdx.x;
    const int wv   = tid >> 6;
    const int lane = tid & 63;
    const int tok0 = blockIdx.x * 64;

    float* xs = smem + wv * (2 * BK * LD);   // this wave's x double-buffer

    // staging: lane covers token rows {srow,+16,+32,+48}, k-chunk skc..skc+3
    const int srow = lane >> 2;          // 0..15
    const int skc  = (lane & 3) * 4;     // 0,4,8,12

    // compute: 8x8 micro-tile
    const int trow = (lane & 7) * 8;     // first of 8 tokens
    const int ecol = (lane >> 3) * 8;    // first of 8 experts

    const float* xp = x + (size_t)(tok0 + srow) * D_MODEL + (size_t)wv * KW + skc;
    const float* wp = wt + (size_t)wv * KW * N_EXP + ecol;   // row k: wp + k*64

    float acc[8][8] = {};

#define LOADR(q, roff) (*(const float4*)((q) + (size_t)(roff) * D_MODEL))
#define STORE_TILE(buf, v, roff) do {                      \
        (buf)[(skc + 0) * LD + srow + (roff)] = (v).x;     \
        (buf)[(skc + 1) * LD + srow + (roff)] = (v).y;     \
        (buf)[(skc + 2) * LD + srow + (roff)] = (v).z;     \
        (buf)[(skc + 3) * LD + srow + (roff)] = (v).w;     \
    } while (0)

    // prologue: x tile 0 -> buffer 0
    {
        float4 a0 = LOADR(xp, 0),  a1 = LOADR(xp, 16);
        float4 a2 = LOADR(xp, 32), a3 = LOADR(xp, 48);
        STORE_TILE(xs, a0, 0);  STORE_TILE(xs, a1, 16);
        STORE_TILE(xs, a2, 32); STORE_TILE(xs, a3, 48);
    }

    auto compute_tile = [&](const float* xb, int kbase) {
#pragma unroll 4
        for (int k = 0; k < BK; ++k) {
            const float* xr = xb + k * LD + trow;
            float4 xa = *(const float4*)xr;
            float4 xc = *(const float4*)(xr + 4);
            const float* wr = wp + (size_t)(kbase + k) * N_EXP;
            float4 wa = *(const float4*)wr;
            float4 wc = *(const float4*)(wr + 4);
            float xf[8] = {xa.x, xa.y, xa.z, xa.w, xc.x, xc.y, xc.z, xc.w};
            float wf[8] = {wa.x, wa.y, wa.z, wa.w, wc.x, wc.y, wc.z, wc.w};
#pragma unroll
            for (int i = 0; i < 8; ++i)
#pragma unroll
                for (int j = 0; j < 8; ++j)
                    acc[i][j] = fmaf(xf[i], wf[j], acc[i][j]);
        }
    };

    for (int t = 0; t < NT - 1; ++t) {
        float* xb = xs + (t & 1) * (BK * LD);
        float* xn = xs + ((t + 1) & 1) * (BK * LD);

        // issue next x tile's global loads; latency hides under 2048cyc of FMA
        const float* xq = xp + (t + 1) * BK;
        float4 a0 = LOADR(xq, 0),  a1 = LOADR(xq, 16);
        float4 a2 = LOADR(xq, 32), a3 = LOADR(xq, 48);

        compute_tile(xb, t * BK);

        STORE_TILE(xn, a0, 0);  STORE_TILE(xn, a1, 16);
        STORE_TILE(xn, a2, 32); STORE_TILE(xn, a3, 48);
    }
    compute_tile(xs + ((NT - 1) & 1) * (BK * LD), (NT - 1) * BK);

    // ---- epilogue: 2-stage cross-wave k-reduce + softmax/top2 ----
    __syncthreads();                       // all waves done with staging reads

    float* tile = smem + (wv & 3) * 4096;  // 4 shared 64x64 tiles
    if (wv < 4) {
#pragma unroll
        for (int i = 0; i < 8; ++i) {
            *(float4*)&tile[(trow + i) * 64 + ecol] =
                make_float4(acc[i][0], acc[i][1], acc[i][2], acc[i][3]);
            *(float4*)&tile[(trow + i) * 64 + ecol + 4] =
                make_float4(acc[i][4], acc[i][5], acc[i][6], acc[i][7]);
        }
    }
    __syncthreads();
    if (wv >= 4) {                         // RMW-add (disjoint elements/thread)
#pragma unroll
        for (int i = 0; i < 8; ++i) {
            float4* tp = (float4*)&tile[(trow + i) * 64 + ecol];
            float4 v0 = tp[0], v1 = tp[1];
            v0.x += acc[i][0]; v0.y += acc[i][1];
            v0.z += acc[i][2]; v0.w += acc[i][3];
            v1.x += acc[i][4]; v1.y += acc[i][5];
            v1.z += acc[i][6]; v1.w += acc[i][7];
            tp[0] = v0; tp[1] = v1;
        }
    }
    __syncthreads();

    float p_acc = 0.f, f_acc = 0.f;        // lane = expert
#pragma unroll 1
    for (int it = 0; it < 8; ++it) {
        const int tl = wv * 8 + it;        // local token
        const int o  = tl * 64 + lane;
        float logit = smem[o] + smem[4096 + o] + smem[8192 + o] + smem[12288 + o];

        // top-1: value max-reduce, then ballot -> lowest tied index
        float m = logit;
#pragma unroll
        for (int off = 32; off; off >>= 1)
            m = fmaxf(m, __shfl_xor(m, off, 64));
        unsigned long long b1 = __ballot(logit == m);
        int i1 = __ffsll(b1) - 1;

        float p = expf(logit - m);
        float denom = p;
#pragma unroll
        for (int off = 32; off; off >>= 1)
            denom += __shfl_xor(denom, off, 64);

        p_acc += p / denom;                // router_probs[token][lane]
        if (lane == i1) f_acc += 1.f;

        // top-2: mask i1, repeat
        float lx = (lane == i1) ? -__builtin_inff() : logit;
        float m2 = lx;
#pragma unroll
        for (int off = 32; off; off >>= 1)
            m2 = fmaxf(m2, __shfl_xor(m2, off, 64));
        unsigned long long b2 = __ballot(lx == m2);
        int i2 = __ffsll(b2) - 1;

        if (lane == 0) {
            float p1 = 1.0f / denom;               // exp(m-m)/denom
            float p2 = expf(m2 - m) / denom;
            float s12 = p1 + p2;
            int token = tok0 + tl;
            ((float2*)out)[token] = make_float2(p1 / s12, p2 / s12);
            ((float2*)(out + 2 * N_TOKENS))[token] =
                make_float2((float)i1, (float)i2);
        }
    }

    // block-level p/f sums -> block_sums (no atomics)
    float* pf = smem + 4 * 4096;           // [0,512): p, [512,1024): f
    pf[wv * 64 + lane]       = p_acc;
    pf[512 + wv * 64 + lane] = f_acc;
    __syncthreads();
    if (tid < N_EXP) {
        float ps = 0.f, fs = 0.f;
#pragma unroll
        for (int h = 0; h < NW; ++h) {
            ps += pf[h * 64 + tid];
            fs += pf[512 + h * 64 + tid];
        }
        block_sums[(size_t)blockIdx.x * 128 + tid]      = ps;
        block_sums[(size_t)blockIdx.x * 128 + 64 + tid] = fs;
    }
}

// ---------------------------------------------------------------------------
// Final: reduce 256 blocks' p/f sums, loss = 0.01 * sum_e (f_e/N)*(p_e/N).
// ---------------------------------------------------------------------------
__global__ void __launch_bounds__(256)
router_final(const float* __restrict__ block_sums, float* __restrict__ out) {
    __shared__ float sp[4][N_EXP];
    __shared__ float sf[4][N_EXP];

    int tid  = threadIdx.x;
    int wv   = tid >> 6;
    int lane = tid & 63;

    float ps = 0.f, fs = 0.f;
#pragma unroll 8
    for (int b = wv * (NBLK / 4); b < (wv + 1) * (NBLK / 4); ++b) {
        ps += block_sums[(size_t)b * 128 + lane];
        fs += block_sums[(size_t)b * 128 + 64 + lane];
    }
    sp[wv][lane] = ps;
    sf[wv][lane] = fs;
    __syncthreads();

    if (tid < N_EXP) {
        float pt = sp[0][tid] + sp[1][tid] + sp[2][tid] + sp[3][tid];
        float ft = sf[0][tid] + sf[1][tid] + sf[2][tid] + sf[3][tid];
        float v = pt * ft;
#pragma unroll
        for (int off = 1; off < 64; off <<= 1)
            v += __shfl_xor(v, off, 64);
        if (tid == 0)
            out[4 * N_TOKENS] = 0.01f * v / ((float)N_TOKENS * (float)N_TOKENS);
    }
}

// ---------------------------------------------------------------------------
extern "C" void kernel_launch(void* const* d_in, const int* in_sizes, int n_in,
                              void* d_out, int out_size, void* d_ws, size_t ws_size,
                              hipStream_t stream) {
    (void)in_sizes; (void)n_in; (void)out_size; (void)ws_size;
    const float* x = (const float*)d_in[0];
    const float* w = (const float*)d_in[1];
    float* out = (float*)d_out;

    float* wT = (float*)d_ws;                            // 4096*64*4 = 1 MB
    float* block_sums = wT + (size_t)D_MODEL * N_EXP;    // 128 KB

    transpose_w<<<D_MODEL / 64, 256, 0, stream>>>(w, wT);
    router_fused<<<NBLK, 512, 0, stream>>>(x, wT, out, block_sums);
    router_final<<<1, 256, 0, stream>>>(block_sums, out);
}

// Round 5
// 417.290 us; speedup vs baseline: 1.1990x; 1.1975x over previous
//
#include <hip/hip_runtime.h>
#include <math.h>

#define N_TOKENS 16384
#define D_MODEL  4096
#define N_EXP    64

#define TOKB 32                 // tokens per block
#define NW   8                  // waves per block
#define KW   (D_MODEL / NW)     // 512 k per wave
#define BK   8                  // k-depth per LDS tile
#define NT   (KW / BK)          // 64 tiles per wave
#define LDX  36                 // x LDS leading dim: 32 + 4 pad
#define LDW  68                 // w LDS leading dim: 64 + 4 pad
#define SZW  (2 * BK * LDX + 2 * BK * LDW)   // 1664 floats per wave
#define NBLK (N_TOKENS / TOKB)  // 512 blocks -> 2 blocks/CU

// ---------------------------------------------------------------------------
// Pre-pass: w[64][4096] -> wT[4096][64] so staging loads are coalesced float4
// and LDS stores are ds_write_b128 (no scalar transpose in the hot kernel).
// ---------------------------------------------------------------------------
__global__ void __launch_bounds__(256)
transpose_w(const float* __restrict__ w, float* __restrict__ wt) {
    __shared__ float t[64][LDW];
    const int k0 = blockIdx.x * 64;
    const int kc = (threadIdx.x & 15) * 4;   // k offset within tile
    const int e0 = threadIdx.x >> 4;         // 0..15
#pragma unroll
    for (int p = 0; p < 4; ++p) {
        int e = p * 16 + e0;
        float4 v = *(const float4*)(w + (size_t)e * D_MODEL + k0 + kc);
        t[kc + 0][e] = v.x; t[kc + 1][e] = v.y;
        t[kc + 2][e] = v.z; t[kc + 3][e] = v.w;
    }
    __syncthreads();
    const int kr = threadIdx.x >> 2;         // 0..63
    const int ec = (threadIdx.x & 3) * 16;
#pragma unroll
    for (int j = 0; j < 4; ++j) {
        float4 v = make_float4(t[kr][ec + j * 4 + 0], t[kr][ec + j * 4 + 1],
                               t[kr][ec + j * 4 + 2], t[kr][ec + j * 4 + 3]);
        *(float4*)(wt + (size_t)(k0 + kr) * N_EXP + ec + j * 4) = v;
    }
}

// ---------------------------------------------------------------------------
// Fused router. Block = 32 tokens, 512 threads = 8 waves; wave wv owns the
// full 32x64 logit tile for k in [wv*512, wv*512+512).
//   Grid = 512 blocks -> 2 blocks/CU -> 16 waves/CU = 4 waves/SIMD (rounds
//   1-4 were structurally capped at 1 block/CU: 64-token blocks = 256 blocks).
//   - x AND w staged in per-wave double-buffered LDS (inner loop is pure
//     LDS+FMA; round 3/4's global-w loads exposed ~200cy L2 latency/k-group)
//   - per k-step: 1 ds_read_b128 (x, 8-way broadcast) + 2 ds_read_b128 (w,
//     8-way broadcast) -> 32 v_fmac (64 SIMD-cyc); all LDS patterns <=2-way
//   - BK=8 keeps prefetch at 3 float4 live regs -> ~78 VGPR demand: no
//     launch_bounds min-waves arg (it clamped to 64 VGPRs in rounds 3/4)
//   - NO barriers in main loop (per-wave buffers)
// Epilogue: 2-stage tile reduce (waves 0-3 write 4 tiles of 32x64, waves 4-7
// RMW-add), 4-buffer sum -> logits, softmax/top2 with ballot-argmax (ties ->
// lowest index, matching jax.lax.top_k), per-block p/f sums (no atomics).
// ---------------------------------------------------------------------------
__global__ void __launch_bounds__(512)
router_fused(const float* __restrict__ x, const float* __restrict__ wt,
             float* __restrict__ out, float* __restrict__ block_sums) {
    // staging: 8 waves x 1664 floats = 13312 floats = 53248 B -> 2 blocks/CU.
    // epilogue reuse: 4 x [32][64] tiles at [0,8192), p/f sums at [8192,9216).
    __shared__ float smem[NW * SZW];

    const int tid  = threadIdx.x;
    const int wv   = tid >> 6;
    const int lane = tid & 63;
    const int tok0 = blockIdx.x * TOKB;

    float* xs = smem + wv * SZW;             // x double-buffer (2 x 288)
    float* wl = xs + 2 * BK * LDX;           // w double-buffer (2 x 544)

    // x staging: lane covers token row srow, k-chunk skc..skc+3
    const int srow = lane >> 1;              // 0..31
    const int skc  = (lane & 1) * 4;         // 0 or 4
    // w staging: lane covers k-row kk, experts ec..ec+7
    const int kk   = lane >> 3;              // 0..7
    const int ec   = (lane & 7) * 8;         // 0..56

    // compute: 4 tokens x 8 experts micro-tile
    const int trow = (lane & 7) * 4;         // first of 4 tokens
    const int ecol = (lane >> 3) * 8;        // first of 8 experts

    const float* xp = x + (size_t)(tok0 + srow) * D_MODEL + (size_t)wv * KW + skc;
    const float* wp = wt + ((size_t)wv * KW + kk) * N_EXP + ec;

    float acc[4][8] = {};

#define STORE_X(buf, v) do {                               \
        (buf)[(skc + 0) * LDX + srow] = (v).x;             \
        (buf)[(skc + 1) * LDX + srow] = (v).y;             \
        (buf)[(skc + 2) * LDX + srow] = (v).z;             \
        (buf)[(skc + 3) * LDX + srow] = (v).w;             \
    } while (0)
#define STORE_W(buf, u0, u1) do {                          \
        *(float4*)&(buf)[kk * LDW + ec]     = (u0);        \
        *(float4*)&(buf)[kk * LDW + ec + 4] = (u1);        \
    } while (0)

    // prologue: tile 0 -> buffer 0
    {
        float4 a  = *(const float4*)(xp);
        float4 b0 = *(const float4*)(wp);
        float4 b1 = *(const float4*)(wp + 4);
        STORE_X(xs, a);
        STORE_W(wl, b0, b1);
    }

    auto compute_tile = [&](const float* xb, const float* wb) {
#pragma unroll
        for (int k = 0; k < BK; ++k) {
            float4 xa = *(const float4*)&xb[k * LDX + trow];
            float4 wa = *(const float4*)&wb[k * LDW + ecol];
            float4 wc = *(const float4*)&wb[k * LDW + ecol + 4];
            float xf[4] = {xa.x, xa.y, xa.z, xa.w};
            float wf[8] = {wa.x, wa.y, wa.z, wa.w, wc.x, wc.y, wc.z, wc.w};
#pragma unroll
            for (int i = 0; i < 4; ++i)
#pragma unroll
                for (int j = 0; j < 8; ++j)
                    acc[i][j] = fmaf(xf[i], wf[j], acc[i][j]);
        }
    };

#pragma unroll 2
    for (int t = 0; t < NT - 1; ++t) {
        float* xb = xs + (t & 1) * (BK * LDX);
        float* wb = wl + (t & 1) * (BK * LDW);
        float* xn = xs + ((t + 1) & 1) * (BK * LDX);
        float* wn = wl + ((t + 1) & 1) * (BK * LDW);

        // issue next tile's global loads (hide under this tile's 512cyc FMA)
        float4 a  = *(const float4*)(xp + (t + 1) * BK);
        float4 b0 = *(const float4*)(wp + (size_t)(t + 1) * BK * N_EXP);
        float4 b1 = *(const float4*)(wp + (size_t)(t + 1) * BK * N_EXP + 4);

        compute_tile(xb, wb);

        STORE_X(xn, a);
        STORE_W(wn, b0, b1);
    }
    compute_tile(xs + ((NT - 1) & 1) * (BK * LDX),
                 wl + ((NT - 1) & 1) * (BK * LDW));

    // ---- epilogue: 2-stage cross-wave k-reduce + softmax/top2 ----
    __syncthreads();                       // all waves done with staging reads

    float* tile = smem + (wv & 3) * (TOKB * N_EXP);   // 4 shared 32x64 tiles
    if (wv < 4) {
#pragma unroll
        for (int i = 0; i < 4; ++i) {
            *(float4*)&tile[(trow + i) * 64 + ecol] =
                make_float4(acc[i][0], acc[i][1], acc[i][2], acc[i][3]);
            *(float4*)&tile[(trow + i) * 64 + ecol + 4] =
                make_float4(acc[i][4], acc[i][5], acc[i][6], acc[i][7]);
        }
    }
    __syncthreads();
    if (wv >= 4) {                         // RMW-add (disjoint elements/thread)
#pragma unroll
        for (int i = 0; i < 4; ++i) {
            float4* tp = (float4*)&tile[(trow + i) * 64 + ecol];
            float4 v0 = tp[0], v1 = tp[1];
            v0.x += acc[i][0]; v0.y += acc[i][1];
            v0.z += acc[i][2]; v0.w += acc[i][3];
            v1.x += acc[i][4]; v1.y += acc[i][5];
            v1.z += acc[i][6]; v1.w += acc[i][7];
            tp[0] = v0; tp[1] = v1;
        }
    }
    __syncthreads();

    float p_acc = 0.f, f_acc = 0.f;        // lane = expert
#pragma unroll 1
    for (int it = 0; it < 4; ++it) {
        const int tl = wv * 4 + it;        // local token (8 waves x 4 = 32)
        const int o  = tl * 64 + lane;
        float logit = smem[o] + smem[2048 + o] + smem[4096 + o] + smem[6144 + o];

        // top-1: value max-reduce, then ballot -> lowest tied index
        float m = logit;
#pragma unroll
        for (int off = 32; off; off >>= 1)
            m = fmaxf(m, __shfl_xor(m, off, 64));
        unsigned long long b1 = __ballot(logit == m);
        int i1 = __ffsll(b1) - 1;

        float p = expf(logit - m);
        float denom = p;
#pragma unroll
        for (int off = 32; off; off >>= 1)
            denom += __shfl_xor(denom, off, 64);

        p_acc += p / denom;                // router_probs[token][lane]
        if (lane == i1) f_acc += 1.f;

        // top-2: mask i1, repeat
        float lx = (lane == i1) ? -__builtin_inff() : logit;
        float m2 = lx;
#pragma unroll
        for (int off = 32; off; off >>= 1)
            m2 = fmaxf(m2, __shfl_xor(m2, off, 64));
        unsigned long long b2 = __ballot(lx == m2);
        int i2 = __ffsll(b2) - 1;

        if (lane == 0) {
            float p1 = 1.0f / denom;               // exp(m-m)/denom
            float p2 = expf(m2 - m) / denom;
            float s12 = p1 + p2;
            int token = tok0 + tl;
            ((float2*)out)[token] = make_float2(p1 / s12, p2 / s12);
            ((float2*)(out + 2 * N_TOKENS))[token] =
                make_float2((float)i1, (float)i2);
        }
    }

    // block-level p/f sums -> block_sums (no atomics)
    float* pf = smem + 4 * TOKB * N_EXP;   // [0,512): p, [512,1024): f
    pf[wv * 64 + lane]       = p_acc;
    pf[512 + wv * 64 + lane] = f_acc;
    __syncthreads();
    if (tid < N_EXP) {
        float ps = 0.f, fs = 0.f;
#pragma unroll
        for (int h = 0; h < NW; ++h) {
            ps += pf[h * 64 + tid];
            fs += pf[512 + h * 64 + tid];
        }
        block_sums[(size_t)blockIdx.x * 128 + tid]      = ps;
        block_sums[(size_t)blockIdx.x * 128 + 64 + tid] = fs;
    }
}

// ---------------------------------------------------------------------------
// Final: reduce 512 blocks' p/f sums, loss = 0.01 * sum_e (f_e/N)*(p_e/N).
// ---------------------------------------------------------------------------
__global__ void __launch_bounds__(256)
router_final(const float* __restrict__ block_sums, float* __restrict__ out) {
    __shared__ float sp[4][N_EXP];
    __shared__ float sf[4][N_EXP];

    int tid  = threadIdx.x;
    int wv   = tid >> 6;
    int lane = tid & 63;

    float ps = 0.f, fs = 0.f;
#pragma unroll 8
    for (int b = wv * (NBLK / 4); b < (wv + 1) * (NBLK / 4); ++b) {
        ps += block_sums[(size_t)b * 128 + lane];
        fs += block_sums[(size_t)b * 128 + 64 + lane];
    }
    sp[wv][lane] = ps;
    sf[wv][lane] = fs;
    __syncthreads();

    if (tid < N_EXP) {
        float pt = sp[0][tid] + sp[1][tid] + sp[2][tid] + sp[3][tid];
        float ft = sf[0][tid] + sf[1][tid] + sf[2][tid] + sf[3][tid];
        float v = pt * ft;
#pragma unroll
        for (int off = 1; off < 64; off <<= 1)
            v += __shfl_xor(v, off, 64);
        if (tid == 0)
            out[4 * N_TOKENS] = 0.01f * v / ((float)N_TOKENS * (float)N_TOKENS);
    }
}

// ---------------------------------------------------------------------------
extern "C" void kernel_launch(void* const* d_in, const int* in_sizes, int n_in,
                              void* d_out, int out_size, void* d_ws, size_t ws_size,
                              hipStream_t stream) {
    (void)in_sizes; (void)n_in; (void)out_size; (void)ws_size;
    const float* x = (const float*)d_in[0];
    const float* w = (const float*)d_in[1];
    float* out = (float*)d_out;

    float* wT = (float*)d_ws;                            // 4096*64*4 = 1 MB
    float* block_sums = wT + (size_t)D_MODEL * N_EXP;    // 512*128*4 = 256 KB

    transpose_w<<<D_MODEL / 64, 256, 0, stream>>>(w, wT);
    router_fused<<<NBLK, 512, 0, stream>>>(x, wT, out, block_sums);
    router_final<<<1, 256, 0, stream>>>(block_sums, out);
}